// Round 12
// baseline (90.841 us; speedup 1.0000x reference)
//
#include <hip/hip_runtime.h>

typedef __attribute__((ext_vector_type(8))) _Float16 half8;
typedef __attribute__((ext_vector_type(2))) __fp16 fp16x2;
typedef __attribute__((ext_vector_type(4))) float f32x4;
typedef __attribute__((ext_vector_type(16))) float f32x16;

constexpr int Bc = 2, Sc = 2048, Dc = 1024, Hc = 16, HDc = 64;

// LDS swizzle for [rows][64] f16 tiles (qkv_proj x-tile only).
__device__ __forceinline__ int swz(int row, int colh) {
  return row * 64 + (colh ^ ((row & 7) * 8));
}

#define PKU(a, b) __builtin_bit_cast(unsigned, __builtin_amdgcn_cvt_pkrtz((a), (b)))

// pack 2 groups-of-4 f32, exchange halves across hi split, store fragment half8.
#define PACK_STORE(vA0, vA1, vA2, vA3, vB0, vB1, vB2, vB3, ptr) {        \
  unsigned W0 = PKU(vA0, vA1), W1 = PKU(vA2, vA3);                       \
  unsigned X0 = PKU(vB0, vB1), X1 = PKU(vB2, vB3);                       \
  unsigned s0_ = (unsigned)__shfl_xor((int)(hi ? W0 : X0), 32);          \
  unsigned s1_ = (unsigned)__shfl_xor((int)(hi ? W1 : X1), 32);          \
  union { unsigned u[4]; half8 h8; } P_;                                 \
  P_.u[0] = hi ? s0_ : W0; P_.u[1] = hi ? s1_ : W1;                      \
  P_.u[2] = hi ? X0 : s0_; P_.u[3] = hi ? X1 : s1_;                      \
  *(half8*)(ptr) = P_.h8; }

// ---------------------------------------------------------------------------
// prep_all: fused prep_w (blocks 0..47) + prep_wo (blocks 48..303).
__global__ __launch_bounds__(256) void prep_all(
    const float* __restrict__ Wq, const float* __restrict__ Wk,
    const float* __restrict__ Wv, const float* __restrict__ Wo,
    _Float16* __restrict__ WT, _Float16* __restrict__ WoT) {
  __shared__ float T[64][68];
  const int tid = threadIdx.x;
  if (blockIdx.x < 48) {
    const int m = blockIdx.x >> 4;
    const int h = blockIdx.x & 15;
    const float* src = (m == 0 ? Wq : (m == 1 ? Wk : Wv)) + (size_t)h * 4096;
    const float scale = (m == 0) ? 0.125f * 1.44269504088896f : 1.0f;
#pragma unroll
    for (int i = 0; i < 4; ++i) {
      int r = (tid >> 4) + 16 * i, c4 = (tid & 15) * 4;
      *(float4*)&T[r][c4] = *(const float4*)(src + r * 64 + c4);
    }
    __syncthreads();
    _Float16* dst = WT + ((size_t)m * 16 + h) * 4096;
#pragma unroll
    for (int i = 0; i < 4; ++i) {
      int e = (tid >> 4) + 16 * i, d4 = (tid & 15) * 4;
      union { _Float16 hh[4]; unsigned long long u; } pk;
#pragma unroll
      for (int j = 0; j < 4; ++j) pk.hh[j] = (_Float16)(T[d4 + j][e] * scale);
      *(unsigned long long*)(dst + (size_t)e * 64 + d4) = pk.u;
    }
  } else {
    const int idx = blockIdx.x - 48;
    const int hh = idx & 15;
    const int n0 = (idx >> 4) * 64;
#pragma unroll
    for (int i = 0; i < 4; ++i) {
      int g = tid + i * 256;
      int e = g >> 4, c4 = (g & 15) * 4;
      *(float4*)&T[e][c4] = *(const float4*)(Wo + (size_t)(e * 16 + hh) * Dc + n0 + c4);
    }
    __syncthreads();
#pragma unroll
    for (int i = 0; i < 4; ++i) {
      int g = tid + i * 256;
      int c = g >> 4, e4 = (g & 15) * 4;
      union { _Float16 h[4]; unsigned long long u; } pk;
      pk.h[0] = (_Float16)T[e4 + 0][c];
      pk.h[1] = (_Float16)T[e4 + 1][c];
      pk.h[2] = (_Float16)T[e4 + 2][c];
      pk.h[3] = (_Float16)T[e4 + 3][c];
      *(unsigned long long*)(WoT + (size_t)(n0 + c) * Dc + hh * 64 + e4) = pk.u;
    }
  }
}

// ---------------------------------------------------------------------------
// qkv_proj (R8 known-good): LDS-staged x, 4 waves x 32 s-rows.
// Fragment layouts (chunk = 512 halves, addr = chunk*512 + lane*8 + elem):
//  Q'[(bh*64+qt)*4 + (e>>4)]                lane=((e>>3)&1)*32+(s&31), elem=e&7
//  K'[(bh*32+kt)*8 + ((s>>5)&1)*4 + (e>>4)] lane=((e>>3)&1)*32+(s&31), elem=e&7
//  V'[(bh*32+kt)*8 + (e>>5)*4 + ((s>>4)&3)] lane=((s>>3)&1)*32+(e&31), elem=s&7
__global__ __launch_bounds__(256) void qkv_proj(
    const float* __restrict__ x, const _Float16* __restrict__ WT,
    _Float16* __restrict__ Qp, _Float16* __restrict__ Kp,
    _Float16* __restrict__ Vp) {
  const int h = blockIdx.x & 15;
  const int st = (blockIdx.x >> 4) & 15;
  const int b = blockIdx.x >> 8;
  const int s0 = st * 128;
  __shared__ __align__(16) _Float16 xs[128 * 64];
  const int tid = threadIdx.x;
#pragma unroll
  for (int i = 0; i < 4; ++i) {
    int r = (tid >> 3) + 32 * i;
    int c8 = (tid & 7) * 8;
    const float* xp = x + ((size_t)(b * Sc + s0 + r)) * Dc + h * 64 + c8;
    float4 u0 = *(const float4*)xp;
    float4 u1 = *(const float4*)(xp + 4);
    union { fp16x2 h2[4]; half8 h8; } pk;
    pk.h2[0] = __builtin_amdgcn_cvt_pkrtz(u0.x, u0.y);
    pk.h2[1] = __builtin_amdgcn_cvt_pkrtz(u0.z, u0.w);
    pk.h2[2] = __builtin_amdgcn_cvt_pkrtz(u1.x, u1.y);
    pk.h2[3] = __builtin_amdgcn_cvt_pkrtz(u1.z, u1.w);
    *(half8*)&xs[swz(r, c8)] = pk.h8;
  }
  __syncthreads();
  const int l = tid & 63, w = tid >> 6;
  const int lq = l & 31, hi = l >> 5;
  half8 xa[4];
#pragma unroll
  for (int c = 0; c < 4; ++c)
    xa[c] = *(const half8*)&xs[swz(32 * w + lq, c * 16 + hi * 8)];

  const _Float16* WTq = WT + (size_t)h * 4096;
  const _Float16* WTk = WT + (size_t)(16 + h) * 4096;
  const _Float16* WTv = WT + (size_t)(32 + h) * 4096;
  f32x16 Qt[2] = {}, Kt[2] = {}, Vd[2] = {};
#pragma unroll
  for (int et = 0; et < 2; ++et) {
#pragma unroll
    for (int c = 0; c < 4; ++c) {
      const int off = (32 * et + lq) * 64 + c * 16 + hi * 8;
      half8 wqf = *(const half8*)(WTq + off);
      half8 wkf = *(const half8*)(WTk + off);
      half8 wvf = *(const half8*)(WTv + off);
      Qt[et] = __builtin_amdgcn_mfma_f32_32x32x16_f16(wqf, xa[c], Qt[et], 0, 0, 0);
      Kt[et] = __builtin_amdgcn_mfma_f32_32x32x16_f16(wkf, xa[c], Kt[et], 0, 0, 0);
      Vd[et] = __builtin_amdgcn_mfma_f32_32x32x16_f16(xa[c], wvf, Vd[et], 0, 0, 0);
    }
  }
  const int bh = b * Hc + h;
  const int qt_ = 4 * st + w;
  const int ktile = 2 * st + (w >> 1);
  _Float16* qdst = Qp + (((size_t)(bh * 64 + qt_) * 4) << 9) + (l << 3);
  _Float16* kdst = Kp + (((size_t)((bh * 32 + ktile) * 8) + (w & 1) * 4) << 9) + (l << 3);
  _Float16* vdst = Vp + (((size_t)(bh * 32 + ktile) * 8) << 9) + (l << 3);

  PACK_STORE(Qt[0][0], Qt[0][1], Qt[0][2], Qt[0][3], Qt[0][4], Qt[0][5], Qt[0][6], Qt[0][7], qdst + (0 << 9));
  PACK_STORE(Qt[0][8], Qt[0][9], Qt[0][10], Qt[0][11], Qt[0][12], Qt[0][13], Qt[0][14], Qt[0][15], qdst + (1 << 9));
  PACK_STORE(Qt[1][0], Qt[1][1], Qt[1][2], Qt[1][3], Qt[1][4], Qt[1][5], Qt[1][6], Qt[1][7], qdst + (2 << 9));
  PACK_STORE(Qt[1][8], Qt[1][9], Qt[1][10], Qt[1][11], Qt[1][12], Qt[1][13], Qt[1][14], Qt[1][15], qdst + (3 << 9));

  PACK_STORE(Kt[0][0], Kt[0][1], Kt[0][2], Kt[0][3], Kt[0][4], Kt[0][5], Kt[0][6], Kt[0][7], kdst + (0 << 9));
  PACK_STORE(Kt[0][8], Kt[0][9], Kt[0][10], Kt[0][11], Kt[0][12], Kt[0][13], Kt[0][14], Kt[0][15], kdst + (1 << 9));
  PACK_STORE(Kt[1][0], Kt[1][1], Kt[1][2], Kt[1][3], Kt[1][4], Kt[1][5], Kt[1][6], Kt[1][7], kdst + (2 << 9));
  PACK_STORE(Kt[1][8], Kt[1][9], Kt[1][10], Kt[1][11], Kt[1][12], Kt[1][13], Kt[1][14], Kt[1][15], kdst + (3 << 9));

#pragma unroll
  for (int et = 0; et < 2; ++et) {
    PACK_STORE(Vd[et][0], Vd[et][1], Vd[et][2], Vd[et][3], Vd[et][4], Vd[et][5], Vd[et][6], Vd[et][7],
               vdst + ((size_t)(et * 4 + ((2 * w + 0) & 3)) << 9));
    PACK_STORE(Vd[et][8], Vd[et][9], Vd[et][10], Vd[et][11], Vd[et][12], Vd[et][13], Vd[et][14], Vd[et][15],
               vdst + ((size_t)(et * 4 + ((2 * w + 1) & 3)) << 9));
  }
}

// ---------------------------------------------------------------------------
// flash_attn v6 (R8 known-good, exact): balanced pairing. Block = (bh, pair),
// 2 waves, 1024 blocks. wave0: qt=63-p kv [0,16); wave1: qt=p fully (store),
// then qt=63-p kv [16,NT). LDS flash-decoding merge; E/O K prefetch.
#define DOB(t, q0v) (((t) * 64 + 32) <= (q0v) + 31)

#define LOADK(KA, KB, t, q0v) {                                               \
  const _Float16* p8 = Kp + (((kvb + (t)) * 8) << 9) + (l << 3);              \
  _Pragma("unroll") for (int c = 0; c < 4; ++c)                               \
    KA[c] = *(const half8*)(p8 + (c << 9));                                   \
  if (DOB(t, q0v)) {                                                          \
    _Pragma("unroll") for (int c = 0; c < 4; ++c)                             \
      KB[c] = *(const half8*)(p8 + ((4 + c) << 9));                           \
  } }

#define STEP(KA, KB, t, q0v) {                                                \
  const int k0 = (t) * 64;                                                    \
  const bool doB = DOB(t, q0v);                                               \
  const int q_g = (q0v) + lq;                                                 \
  const _Float16* vp8 = Vp + (((kvb + (t)) * 8) << 9) + (l << 3);             \
  half8 va[4], vb[4];                                                         \
  _Pragma("unroll") for (int c = 0; c < 4; ++c) {                             \
    va[c] = *(const half8*)(vp8 + (c << 9));                                  \
    vb[c] = *(const half8*)(vp8 + ((4 + c) << 9));                            \
  }                                                                           \
  f32x16 SA = {}, SB = {};                                                    \
  __builtin_amdgcn_s_setprio(1);                                              \
  _Pragma("unroll") for (int c = 0; c < 4; ++c)                               \
    SA = __builtin_amdgcn_mfma_f32_32x32x16_f16(KA[c], qf[c], SA, 0, 0, 0);   \
  if (doB) {                                                                  \
    _Pragma("unroll") for (int c = 0; c < 4; ++c)                             \
      SB = __builtin_amdgcn_mfma_f32_32x32x16_f16(KB[c], qf[c], SB, 0, 0, 0); \
  }                                                                           \
  __builtin_amdgcn_s_setprio(0);                                              \
  if (k0 + 63 > (q0v)) {                                                      \
    _Pragma("unroll") for (int r = 0; r < 16; ++r) {                          \
      const int kk = k0 + (r & 3) + 8 * (r >> 2) + 4 * hi;                    \
      if (kk > q_g) SA[r] = -1e30f;                                           \
      if (doB && kk + 32 > q_g) SB[r] = -1e30f;                               \
    }                                                                         \
  }                                                                           \
  float mx = -1e30f;                                                          \
  _Pragma("unroll") for (int r = 0; r < 16; ++r) mx = fmaxf(mx, SA[r]);       \
  if (doB) {                                                                  \
    _Pragma("unroll") for (int r = 0; r < 16; ++r) mx = fmaxf(mx, SB[r]);     \
  }                                                                           \
  mx = fmaxf(mx, __shfl_xor(mx, 32));                                         \
  if (!__all(mx <= m_run + 4.0f)) {                                           \
    const float mnew = fmaxf(m_run, mx);                                      \
    const float corr = __builtin_amdgcn_exp2f(m_run - mnew);                  \
    l_run *= corr;                                                            \
    _Pragma("unroll") for (int r = 0; r < 16; ++r) { OA[r] *= corr; OB[r] *= corr; } \
    m_run = mnew;                                                             \
  }                                                                           \
  float Pv[32];                                                               \
  float ls = 0.f;                                                             \
  _Pragma("unroll") for (int r = 0; r < 16; ++r) {                            \
    Pv[r] = __builtin_amdgcn_exp2f(SA[r] - m_run);                            \
    ls += Pv[r];                                                              \
  }                                                                           \
  if (doB) {                                                                  \
    _Pragma("unroll") for (int r = 0; r < 16; ++r) {                          \
      Pv[16 + r] = __builtin_amdgcn_exp2f(SB[r] - m_run);                     \
      ls += Pv[16 + r];                                                       \
    }                                                                         \
  }                                                                           \
  ls += __shfl_xor(ls, 32);                                                   \
  l_run += ls;                                                                \
  __builtin_amdgcn_s_setprio(1);                                              \
  _Pragma("unroll") for (int ch = 0; ch < 4; ++ch) {                          \
    if (ch < (doB ? 4 : 2)) {                                                 \
      unsigned W0 = PKU(Pv[ch * 8 + 0], Pv[ch * 8 + 1]);                      \
      unsigned W1 = PKU(Pv[ch * 8 + 2], Pv[ch * 8 + 3]);                      \
      unsigned W2 = PKU(Pv[ch * 8 + 4], Pv[ch * 8 + 5]);                      \
      unsigned W3 = PKU(Pv[ch * 8 + 6], Pv[ch * 8 + 7]);                      \
      unsigned sw0 = (unsigned)__shfl_xor((int)(hi ? W0 : W2), 32);           \
      unsigned sw1 = (unsigned)__shfl_xor((int)(hi ? W1 : W3), 32);           \
      union { unsigned u[4]; half8 h; } pa;                                   \
      pa.u[0] = hi ? sw0 : W0;                                                \
      pa.u[1] = hi ? sw1 : W1;                                                \
      pa.u[2] = hi ? W2 : sw0;                                                \
      pa.u[3] = hi ? W3 : sw1;                                                \
      OA = __builtin_amdgcn_mfma_f32_32x32x16_f16(va[ch], pa.h, OA, 0, 0, 0); \
      OB = __builtin_amdgcn_mfma_f32_32x32x16_f16(vb[ch], pa.h, OB, 0, 0, 0); \
    }                                                                         \
  }                                                                           \
  __builtin_amdgcn_s_setprio(0); }

// runs tiles [t0, t1) of q-tile with base q0v, accumulating online state.
#define RUN_RANGE(t0, t1, q0v) {                                              \
  int t = (t0);                                                               \
  LOADK(kaE, kbE, t, q0v);                                                    \
  for (; t + 2 <= (t1); t += 2) {                                             \
    LOADK(kaO, kbO, t + 1, q0v);                                              \
    STEP(kaE, kbE, t, q0v);                                                   \
    if (t + 2 < (t1)) { LOADK(kaE, kbE, t + 2, q0v); }                        \
    STEP(kaO, kbO, t + 1, q0v);                                               \
  }                                                                           \
  if (t < (t1)) { STEP(kaE, kbE, t, q0v); } }

__global__ __launch_bounds__(128, 2) void flash_attn(
    const _Float16* __restrict__ Qp, const _Float16* __restrict__ Kp,
    const _Float16* __restrict__ Vp, _Float16* __restrict__ attC) {
  const int i = blockIdx.x;
  const int bh = (i & 7) * 4 + ((i >> 3) & 3);   // XCD-grouped
  const int p = i >> 5;                          // pair index 0..31
  const int qlong = 63 - p, qshort = p;
  const int NTL = qlong / 2 + 1;                 // 17..32
  const int b = bh >> 4, h = bh & 15;
  const int tid = threadIdx.x;
  const int wv = tid >> 6, l = tid & 63;
  const int lq = l & 31, hi = l >> 5;
  const size_t kvb = (size_t)bh * 32;

  __shared__ float Osh[8][64][4];
  __shared__ float mlsh[2][64];

  half8 qf[4], kaE[4], kbE[4], kaO[4], kbO[4];
  f32x16 OA = {}, OB = {};
  float m_run = -1e30f, l_run = 0.f;

  if (wv == 0) {
    // long q-tile, kv [0,16): all tiles full
    const int q0 = qlong * 32;
    const _Float16* qb = Qp + (((size_t)(bh * 64 + qlong) * 4) << 9) + (l << 3);
#pragma unroll
    for (int c = 0; c < 4; ++c) qf[c] = *(const half8*)(qb + (c << 9));
    RUN_RANGE(0, 16, q0);
  } else {
    // phase A: short q-tile fully, store
    const int q0s = qshort * 32;
    const int NTS = qshort / 2 + 1;
    const _Float16* qb = Qp + (((size_t)(bh * 64 + qshort) * 4) << 9) + (l << 3);
#pragma unroll
    for (int c = 0; c < 4; ++c) qf[c] = *(const half8*)(qb + (c << 9));
    RUN_RANGE(0, NTS, q0s);
    {
      const float inv = 1.f / l_run;
      _Float16* op = attC + ((size_t)b * Sc + q0s + lq) * Dc + h * 64;
#pragma unroll
      for (int g = 0; g < 4; ++g) {
        union { _Float16 hh[4]; unsigned long long u; } pA, pB;
#pragma unroll
        for (int jj = 0; jj < 4; ++jj) {
          pA.hh[jj] = (_Float16)(OA[4 * g + jj] * inv);
          pB.hh[jj] = (_Float16)(OB[4 * g + jj] * inv);
        }
        *(unsigned long long*)(op + 8 * g + 4 * hi) = pA.u;
        *(unsigned long long*)(op + 32 + 8 * g + 4 * hi) = pB.u;
      }
    }
    // phase B: long q-tile, kv [16, NTL)
    const int q0 = qlong * 32;
    const _Float16* qb2 = Qp + (((size_t)(bh * 64 + qlong) * 4) << 9) + (l << 3);
#pragma unroll
    for (int c = 0; c < 4; ++c) qf[c] = *(const half8*)(qb2 + (c << 9));
#pragma unroll
    for (int r = 0; r < 16; ++r) { OA[r] = 0.f; OB[r] = 0.f; }
    m_run = -1e30f; l_run = 0.f;
    RUN_RANGE(16, NTL, q0);
    // publish partial state
#pragma unroll
    for (int g = 0; g < 4; ++g) {
      float4 a, bq;
      a.x = OA[4 * g + 0]; a.y = OA[4 * g + 1]; a.z = OA[4 * g + 2]; a.w = OA[4 * g + 3];
      bq.x = OB[4 * g + 0]; bq.y = OB[4 * g + 1]; bq.z = OB[4 * g + 2]; bq.w = OB[4 * g + 3];
      *(float4*)&Osh[g][l][0] = a;
      *(float4*)&Osh[4 + g][l][0] = bq;
    }
    mlsh[0][l] = m_run;
    mlsh[1][l] = l_run;
  }
  __syncthreads();
  if (wv == 0) {
    // merge partial states of the long q-tile, store
    const float m1 = mlsh[0][l], l1 = mlsh[1][l];
    const float mm = fmaxf(m_run, m1);
    const float c0 = __builtin_amdgcn_exp2f(m_run - mm);
    const float c1 = __builtin_amdgcn_exp2f(m1 - mm);
    const float linv = 1.f / (l_run * c0 + l1 * c1);
    _Float16* op = attC + ((size_t)b * Sc + qlong * 32 + lq) * Dc + h * 64;
#pragma unroll
    for (int g = 0; g < 4; ++g) {
      const float4 o1a = *(const float4*)&Osh[g][l][0];
      const float4 o1b = *(const float4*)&Osh[4 + g][l][0];
      union { _Float16 hh[4]; unsigned long long u; } pA, pB;
      pA.hh[0] = (_Float16)((OA[4 * g + 0] * c0 + o1a.x * c1) * linv);
      pA.hh[1] = (_Float16)((OA[4 * g + 1] * c0 + o1a.y * c1) * linv);
      pA.hh[2] = (_Float16)((OA[4 * g + 2] * c0 + o1a.z * c1) * linv);
      pA.hh[3] = (_Float16)((OA[4 * g + 3] * c0 + o1a.w * c1) * linv);
      pB.hh[0] = (_Float16)((OB[4 * g + 0] * c0 + o1b.x * c1) * linv);
      pB.hh[1] = (_Float16)((OB[4 * g + 1] * c0 + o1b.y * c1) * linv);
      pB.hh[2] = (_Float16)((OB[4 * g + 2] * c0 + o1b.z * c1) * linv);
      pB.hh[3] = (_Float16)((OB[4 * g + 3] * c0 + o1b.w * c1) * linv);
      *(unsigned long long*)(op + 8 * g + 4 * hi) = pA.u;
      *(unsigned long long*)(op + 32 + 8 * g + 4 * hi) = pB.u;
    }
  }
}

// ---------------------------------------------------------------------------
// out_proj: 64x128 tile (512 blocks), BK=64 (half the barriers of BK=32),
// 4 waves 1x4; LDS pitch 72 halves (2-way bank conflict = free).
__global__ __launch_bounds__(256) void out_proj(
    const _Float16* __restrict__ attC, const _Float16* __restrict__ WoT,
    const float* __restrict__ bo, float* __restrict__ out) {
  const int m0 = blockIdx.x * 64, n0 = blockIdx.y * 128;
  __shared__ __align__(16) _Float16 Alds[64][72];
  __shared__ __align__(16) _Float16 Blds[128][72];
  const int tid = threadIdx.x;
  const int l = tid & 63, w = tid >> 6;
  const int lr = l & 15, lg = l >> 4;
  f32x4 acc[4][2] = {};
  for (int kt = 0; kt < 16; ++kt) {
    const int k0 = kt * 64;
#pragma unroll
    for (int i = 0; i < 2; ++i) {
      const int g = tid + i * 256;
      const int r = g >> 3, c8 = (g & 7) * 8;
      *(half8*)&Alds[r][c8] = *(const half8*)(attC + (size_t)(m0 + r) * Dc + k0 + c8);
    }
#pragma unroll
    for (int i = 0; i < 4; ++i) {
      const int g = tid + i * 256;
      const int r = g >> 3, c8 = (g & 7) * 8;
      *(half8*)&Blds[r][c8] = *(const half8*)(WoT + (size_t)(n0 + r) * Dc + k0 + c8);
    }
    __syncthreads();
#pragma unroll
    for (int kk = 0; kk < 2; ++kk) {
      half8 af[4], bf[2];
#pragma unroll
      for (int i2 = 0; i2 < 4; ++i2) af[i2] = *(const half8*)&Alds[i2 * 16 + lr][kk * 32 + lg * 8];
#pragma unroll
      for (int j = 0; j < 2; ++j) bf[j] = *(const half8*)&Blds[w * 32 + j * 16 + lr][kk * 32 + lg * 8];
#pragma unroll
      for (int i2 = 0; i2 < 4; ++i2)
#pragma unroll
        for (int j = 0; j < 2; ++j)
          acc[i2][j] = __builtin_amdgcn_mfma_f32_16x16x32_f16(af[i2], bf[j], acc[i2][j], 0, 0, 0);
    }
    __syncthreads();
  }
#pragma unroll
  for (int i2 = 0; i2 < 4; ++i2)
#pragma unroll
    for (int j = 0; j < 2; ++j) {
      const int n = n0 + w * 32 + j * 16 + lr;
      const float bias = bo[n];
#pragma unroll
      for (int r = 0; r < 4; ++r) {
        const int m = m0 + i2 * 16 + lg * 4 + r;
        out[(size_t)m * Dc + n] = acc[i2][j][r] + bias;
      }
    }
}

// ---------------------------------------------------------------------------
extern "C" void kernel_launch(void* const* d_in, const int* in_sizes, int n_in,
                              void* d_out, int out_size, void* d_ws, size_t ws_size,
                              hipStream_t stream) {
  const float* x  = (const float*)d_in[0];
  const float* Wq = (const float*)d_in[1];
  const float* Wk = (const float*)d_in[2];
  const float* Wv = (const float*)d_in[3];
  const float* Wo = (const float*)d_in[4];
  const float* bo = (const float*)d_in[5];
  float* out = (float*)d_out;
  char* ws = (char*)d_ws;
  _Float16* Qp   = (_Float16*)(ws);                        // [0,8M)
  _Float16* Kp   = (_Float16*)(ws + (size_t)(8  << 20));   // [8M,16M)
  _Float16* Vp   = (_Float16*)(ws + (size_t)(16 << 20));   // [16M,24M)
  _Float16* WoT  = (_Float16*)(ws + (size_t)(24 << 20));   // [24M,26M)
  _Float16* WT   = (_Float16*)(ws + (size_t)(26 << 20));   // [26M,26.4M) dead after qkv
  _Float16* attC = (_Float16*)(ws + (size_t)(26 << 20));   // [26M,34M) written in flash

  prep_all<<<dim3(304), dim3(256), 0, stream>>>(Wq, Wk, Wv, Wo, WT, WoT);
  qkv_proj<<<dim3(512), dim3(256), 0, stream>>>(x, WT, Qp, Kp, Vp);
  flash_attn<<<dim3(1024), dim3(128), 0, stream>>>(Qp, Kp, Vp, attC);
  out_proj<<<dim3(64, 8), dim3(256), 0, stream>>>(attC, WoT, bo, out);
}

// Round 13
// 75.194 us; speedup vs baseline: 1.2081x; 1.2081x over previous
//
#include <hip/hip_runtime.h>

typedef __attribute__((ext_vector_type(8))) _Float16 half8;
typedef __attribute__((ext_vector_type(2))) __fp16 fp16x2;
typedef __attribute__((ext_vector_type(4))) float f32x4;
typedef __attribute__((ext_vector_type(16))) float f32x16;

constexpr int Bc = 2, Sc = 2048, Dc = 1024, Hc = 16, HDc = 64;

// LDS swizzle for [rows][64] f16 tiles (qkv_proj x-tile only).
__device__ __forceinline__ int swz(int row, int colh) {
  return row * 64 + (colh ^ ((row & 7) * 8));
}

#define PKU(a, b) __builtin_bit_cast(unsigned, __builtin_amdgcn_cvt_pkrtz((a), (b)))

// pack 2 groups-of-4 f32, exchange halves across hi split, store fragment half8.
#define PACK_STORE(vA0, vA1, vA2, vA3, vB0, vB1, vB2, vB3, ptr) {        \
  unsigned W0 = PKU(vA0, vA1), W1 = PKU(vA2, vA3);                       \
  unsigned X0 = PKU(vB0, vB1), X1 = PKU(vB2, vB3);                       \
  unsigned s0_ = (unsigned)__shfl_xor((int)(hi ? W0 : X0), 32);          \
  unsigned s1_ = (unsigned)__shfl_xor((int)(hi ? W1 : X1), 32);          \
  union { unsigned u[4]; half8 h8; } P_;                                 \
  P_.u[0] = hi ? s0_ : W0; P_.u[1] = hi ? s1_ : W1;                      \
  P_.u[2] = hi ? X0 : s0_; P_.u[3] = hi ? X1 : s1_;                      \
  *(half8*)(ptr) = P_.h8; }

// ---------------------------------------------------------------------------
// prep_all: fused prep_w (blocks 0..47) + prep_wo (blocks 48..303).
__global__ __launch_bounds__(256) void prep_all(
    const float* __restrict__ Wq, const float* __restrict__ Wk,
    const float* __restrict__ Wv, const float* __restrict__ Wo,
    _Float16* __restrict__ WT, _Float16* __restrict__ WoT) {
  __shared__ float T[64][68];
  const int tid = threadIdx.x;
  if (blockIdx.x < 48) {
    const int m = blockIdx.x >> 4;
    const int h = blockIdx.x & 15;
    const float* src = (m == 0 ? Wq : (m == 1 ? Wk : Wv)) + (size_t)h * 4096;
    const float scale = (m == 0) ? 0.125f * 1.44269504088896f : 1.0f;
#pragma unroll
    for (int i = 0; i < 4; ++i) {
      int r = (tid >> 4) + 16 * i, c4 = (tid & 15) * 4;
      *(float4*)&T[r][c4] = *(const float4*)(src + r * 64 + c4);
    }
    __syncthreads();
    _Float16* dst = WT + ((size_t)m * 16 + h) * 4096;
#pragma unroll
    for (int i = 0; i < 4; ++i) {
      int e = (tid >> 4) + 16 * i, d4 = (tid & 15) * 4;
      union { _Float16 hh[4]; unsigned long long u; } pk;
#pragma unroll
      for (int j = 0; j < 4; ++j) pk.hh[j] = (_Float16)(T[d4 + j][e] * scale);
      *(unsigned long long*)(dst + (size_t)e * 64 + d4) = pk.u;
    }
  } else {
    const int idx = blockIdx.x - 48;
    const int hh = idx & 15;
    const int n0 = (idx >> 4) * 64;
#pragma unroll
    for (int i = 0; i < 4; ++i) {
      int g = tid + i * 256;
      int e = g >> 4, c4 = (g & 15) * 4;
      *(float4*)&T[e][c4] = *(const float4*)(Wo + (size_t)(e * 16 + hh) * Dc + n0 + c4);
    }
    __syncthreads();
#pragma unroll
    for (int i = 0; i < 4; ++i) {
      int g = tid + i * 256;
      int c = g >> 4, e4 = (g & 15) * 4;
      union { _Float16 h[4]; unsigned long long u; } pk;
      pk.h[0] = (_Float16)T[e4 + 0][c];
      pk.h[1] = (_Float16)T[e4 + 1][c];
      pk.h[2] = (_Float16)T[e4 + 2][c];
      pk.h[3] = (_Float16)T[e4 + 3][c];
      *(unsigned long long*)(WoT + (size_t)(n0 + c) * Dc + hh * 64 + e4) = pk.u;
    }
  }
}

// ---------------------------------------------------------------------------
// qkv_proj (R8 known-good): LDS-staged x, 4 waves x 32 s-rows.
// Fragment layouts (chunk = 512 halves, addr = chunk*512 + lane*8 + elem):
//  Q'[(bh*64+qt)*4 + (e>>4)]                lane=((e>>3)&1)*32+(s&31), elem=e&7
//  K'[(bh*32+kt)*8 + ((s>>5)&1)*4 + (e>>4)] lane=((e>>3)&1)*32+(s&31), elem=e&7
//  V'[(bh*32+kt)*8 + (e>>5)*4 + ((s>>4)&3)] lane=((s>>3)&1)*32+(e&31), elem=s&7
__global__ __launch_bounds__(256) void qkv_proj(
    const float* __restrict__ x, const _Float16* __restrict__ WT,
    _Float16* __restrict__ Qp, _Float16* __restrict__ Kp,
    _Float16* __restrict__ Vp) {
  const int h = blockIdx.x & 15;
  const int st = (blockIdx.x >> 4) & 15;
  const int b = blockIdx.x >> 8;
  const int s0 = st * 128;
  __shared__ __align__(16) _Float16 xs[128 * 64];
  const int tid = threadIdx.x;
#pragma unroll
  for (int i = 0; i < 4; ++i) {
    int r = (tid >> 3) + 32 * i;
    int c8 = (tid & 7) * 8;
    const float* xp = x + ((size_t)(b * Sc + s0 + r)) * Dc + h * 64 + c8;
    float4 u0 = *(const float4*)xp;
    float4 u1 = *(const float4*)(xp + 4);
    union { fp16x2 h2[4]; half8 h8; } pk;
    pk.h2[0] = __builtin_amdgcn_cvt_pkrtz(u0.x, u0.y);
    pk.h2[1] = __builtin_amdgcn_cvt_pkrtz(u0.z, u0.w);
    pk.h2[2] = __builtin_amdgcn_cvt_pkrtz(u1.x, u1.y);
    pk.h2[3] = __builtin_amdgcn_cvt_pkrtz(u1.z, u1.w);
    *(half8*)&xs[swz(r, c8)] = pk.h8;
  }
  __syncthreads();
  const int l = tid & 63, w = tid >> 6;
  const int lq = l & 31, hi = l >> 5;
  half8 xa[4];
#pragma unroll
  for (int c = 0; c < 4; ++c)
    xa[c] = *(const half8*)&xs[swz(32 * w + lq, c * 16 + hi * 8)];

  const _Float16* WTq = WT + (size_t)h * 4096;
  const _Float16* WTk = WT + (size_t)(16 + h) * 4096;
  const _Float16* WTv = WT + (size_t)(32 + h) * 4096;
  f32x16 Qt[2] = {}, Kt[2] = {}, Vd[2] = {};
#pragma unroll
  for (int et = 0; et < 2; ++et) {
#pragma unroll
    for (int c = 0; c < 4; ++c) {
      const int off = (32 * et + lq) * 64 + c * 16 + hi * 8;
      half8 wqf = *(const half8*)(WTq + off);
      half8 wkf = *(const half8*)(WTk + off);
      half8 wvf = *(const half8*)(WTv + off);
      Qt[et] = __builtin_amdgcn_mfma_f32_32x32x16_f16(wqf, xa[c], Qt[et], 0, 0, 0);
      Kt[et] = __builtin_amdgcn_mfma_f32_32x32x16_f16(wkf, xa[c], Kt[et], 0, 0, 0);
      Vd[et] = __builtin_amdgcn_mfma_f32_32x32x16_f16(xa[c], wvf, Vd[et], 0, 0, 0);
    }
  }
  const int bh = b * Hc + h;
  const int qt_ = 4 * st + w;
  const int ktile = 2 * st + (w >> 1);
  _Float16* qdst = Qp + (((size_t)(bh * 64 + qt_) * 4) << 9) + (l << 3);
  _Float16* kdst = Kp + (((size_t)((bh * 32 + ktile) * 8) + (w & 1) * 4) << 9) + (l << 3);
  _Float16* vdst = Vp + (((size_t)(bh * 32 + ktile) * 8) << 9) + (l << 3);

  PACK_STORE(Qt[0][0], Qt[0][1], Qt[0][2], Qt[0][3], Qt[0][4], Qt[0][5], Qt[0][6], Qt[0][7], qdst + (0 << 9));
  PACK_STORE(Qt[0][8], Qt[0][9], Qt[0][10], Qt[0][11], Qt[0][12], Qt[0][13], Qt[0][14], Qt[0][15], qdst + (1 << 9));
  PACK_STORE(Qt[1][0], Qt[1][1], Qt[1][2], Qt[1][3], Qt[1][4], Qt[1][5], Qt[1][6], Qt[1][7], qdst + (2 << 9));
  PACK_STORE(Qt[1][8], Qt[1][9], Qt[1][10], Qt[1][11], Qt[1][12], Qt[1][13], Qt[1][14], Qt[1][15], qdst + (3 << 9));

  PACK_STORE(Kt[0][0], Kt[0][1], Kt[0][2], Kt[0][3], Kt[0][4], Kt[0][5], Kt[0][6], Kt[0][7], kdst + (0 << 9));
  PACK_STORE(Kt[0][8], Kt[0][9], Kt[0][10], Kt[0][11], Kt[0][12], Kt[0][13], Kt[0][14], Kt[0][15], kdst + (1 << 9));
  PACK_STORE(Kt[1][0], Kt[1][1], Kt[1][2], Kt[1][3], Kt[1][4], Kt[1][5], Kt[1][6], Kt[1][7], kdst + (2 << 9));
  PACK_STORE(Kt[1][8], Kt[1][9], Kt[1][10], Kt[1][11], Kt[1][12], Kt[1][13], Kt[1][14], Kt[1][15], kdst + (3 << 9));

#pragma unroll
  for (int et = 0; et < 2; ++et) {
    PACK_STORE(Vd[et][0], Vd[et][1], Vd[et][2], Vd[et][3], Vd[et][4], Vd[et][5], Vd[et][6], Vd[et][7],
               vdst + ((size_t)(et * 4 + ((2 * w + 0) & 3)) << 9));
    PACK_STORE(Vd[et][8], Vd[et][9], Vd[et][10], Vd[et][11], Vd[et][12], Vd[et][13], Vd[et][14], Vd[et][15],
               vdst + ((size_t)(et * 4 + ((2 * w + 1) & 3)) << 9));
  }
}

// ---------------------------------------------------------------------------
// flash_attn v6 (R8 known-good, exact): balanced pairing. Block = (bh, pair),
// 2 waves, 1024 blocks. wave0: qt=63-p kv [0,16); wave1: qt=p fully (store),
// then qt=63-p kv [16,NT). LDS flash-decoding merge; E/O K prefetch.
#define DOB(t, q0v) (((t) * 64 + 32) <= (q0v) + 31)

#define LOADK(KA, KB, t, q0v) {                                               \
  const _Float16* p8 = Kp + (((kvb + (t)) * 8) << 9) + (l << 3);              \
  _Pragma("unroll") for (int c = 0; c < 4; ++c)                               \
    KA[c] = *(const half8*)(p8 + (c << 9));                                   \
  if (DOB(t, q0v)) {                                                          \
    _Pragma("unroll") for (int c = 0; c < 4; ++c)                             \
      KB[c] = *(const half8*)(p8 + ((4 + c) << 9));                           \
  } }

#define STEP(KA, KB, t, q0v) {                                                \
  const int k0 = (t) * 64;                                                    \
  const bool doB = DOB(t, q0v);                                               \
  const int q_g = (q0v) + lq;                                                 \
  const _Float16* vp8 = Vp + (((kvb + (t)) * 8) << 9) + (l << 3);             \
  half8 va[4], vb[4];                                                         \
  _Pragma("unroll") for (int c = 0; c < 4; ++c) {                             \
    va[c] = *(const half8*)(vp8 + (c << 9));                                  \
    vb[c] = *(const half8*)(vp8 + ((4 + c) << 9));                            \
  }                                                                           \
  f32x16 SA = {}, SB = {};                                                    \
  __builtin_amdgcn_s_setprio(1);                                              \
  _Pragma("unroll") for (int c = 0; c < 4; ++c)                               \
    SA = __builtin_amdgcn_mfma_f32_32x32x16_f16(KA[c], qf[c], SA, 0, 0, 0);   \
  if (doB) {                                                                  \
    _Pragma("unroll") for (int c = 0; c < 4; ++c)                             \
      SB = __builtin_amdgcn_mfma_f32_32x32x16_f16(KB[c], qf[c], SB, 0, 0, 0); \
  }                                                                           \
  __builtin_amdgcn_s_setprio(0);                                              \
  if (k0 + 63 > (q0v)) {                                                      \
    _Pragma("unroll") for (int r = 0; r < 16; ++r) {                          \
      const int kk = k0 + (r & 3) + 8 * (r >> 2) + 4 * hi;                    \
      if (kk > q_g) SA[r] = -1e30f;                                           \
      if (doB && kk + 32 > q_g) SB[r] = -1e30f;                               \
    }                                                                         \
  }                                                                           \
  float mx = -1e30f;                                                          \
  _Pragma("unroll") for (int r = 0; r < 16; ++r) mx = fmaxf(mx, SA[r]);       \
  if (doB) {                                                                  \
    _Pragma("unroll") for (int r = 0; r < 16; ++r) mx = fmaxf(mx, SB[r]);     \
  }                                                                           \
  mx = fmaxf(mx, __shfl_xor(mx, 32));                                         \
  if (!__all(mx <= m_run + 4.0f)) {                                           \
    const float mnew = fmaxf(m_run, mx);                                      \
    const float corr = __builtin_amdgcn_exp2f(m_run - mnew);                  \
    l_run *= corr;                                                            \
    _Pragma("unroll") for (int r = 0; r < 16; ++r) { OA[r] *= corr; OB[r] *= corr; } \
    m_run = mnew;                                                             \
  }                                                                           \
  float Pv[32];                                                               \
  float ls = 0.f;                                                             \
  _Pragma("unroll") for (int r = 0; r < 16; ++r) {                            \
    Pv[r] = __builtin_amdgcn_exp2f(SA[r] - m_run);                            \
    ls += Pv[r];                                                              \
  }                                                                           \
  if (doB) {                                                                  \
    _Pragma("unroll") for (int r = 0; r < 16; ++r) {                          \
      Pv[16 + r] = __builtin_amdgcn_exp2f(SB[r] - m_run);                     \
      ls += Pv[16 + r];                                                       \
    }                                                                         \
  }                                                                           \
  ls += __shfl_xor(ls, 32);                                                   \
  l_run += ls;                                                                \
  __builtin_amdgcn_s_setprio(1);                                              \
  _Pragma("unroll") for (int ch = 0; ch < 4; ++ch) {                          \
    if (ch < (doB ? 4 : 2)) {                                                 \
      unsigned W0 = PKU(Pv[ch * 8 + 0], Pv[ch * 8 + 1]);                      \
      unsigned W1 = PKU(Pv[ch * 8 + 2], Pv[ch * 8 + 3]);                      \
      unsigned W2 = PKU(Pv[ch * 8 + 4], Pv[ch * 8 + 5]);                      \
      unsigned W3 = PKU(Pv[ch * 8 + 6], Pv[ch * 8 + 7]);                      \
      unsigned sw0 = (unsigned)__shfl_xor((int)(hi ? W0 : W2), 32);           \
      unsigned sw1 = (unsigned)__shfl_xor((int)(hi ? W1 : W3), 32);           \
      union { unsigned u[4]; half8 h; } pa;                                   \
      pa.u[0] = hi ? sw0 : W0;                                                \
      pa.u[1] = hi ? sw1 : W1;                                                \
      pa.u[2] = hi ? W2 : sw0;                                                \
      pa.u[3] = hi ? W3 : sw1;                                                \
      OA = __builtin_amdgcn_mfma_f32_32x32x16_f16(va[ch], pa.h, OA, 0, 0, 0); \
      OB = __builtin_amdgcn_mfma_f32_32x32x16_f16(vb[ch], pa.h, OB, 0, 0, 0); \
    }                                                                         \
  }                                                                           \
  __builtin_amdgcn_s_setprio(0); }

// runs tiles [t0, t1) of q-tile with base q0v, accumulating online state.
#define RUN_RANGE(t0, t1, q0v) {                                              \
  int t = (t0);                                                               \
  LOADK(kaE, kbE, t, q0v);                                                    \
  for (; t + 2 <= (t1); t += 2) {                                             \
    LOADK(kaO, kbO, t + 1, q0v);                                              \
    STEP(kaE, kbE, t, q0v);                                                   \
    if (t + 2 < (t1)) { LOADK(kaE, kbE, t + 2, q0v); }                        \
    STEP(kaO, kbO, t + 1, q0v);                                               \
  }                                                                           \
  if (t < (t1)) { STEP(kaE, kbE, t, q0v); } }

__global__ __launch_bounds__(128, 2) void flash_attn(
    const _Float16* __restrict__ Qp, const _Float16* __restrict__ Kp,
    const _Float16* __restrict__ Vp, _Float16* __restrict__ attC) {
  const int i = blockIdx.x;
  const int bh = (i & 7) * 4 + ((i >> 3) & 3);   // XCD-grouped
  const int p = i >> 5;                          // pair index 0..31
  const int qlong = 63 - p, qshort = p;
  const int NTL = qlong / 2 + 1;                 // 17..32
  const int b = bh >> 4, h = bh & 15;
  const int tid = threadIdx.x;
  const int wv = tid >> 6, l = tid & 63;
  const int lq = l & 31, hi = l >> 5;
  const size_t kvb = (size_t)bh * 32;

  __shared__ float Osh[8][64][4];
  __shared__ float mlsh[2][64];

  half8 qf[4], kaE[4], kbE[4], kaO[4], kbO[4];
  f32x16 OA = {}, OB = {};
  float m_run = -1e30f, l_run = 0.f;

  if (wv == 0) {
    // long q-tile, kv [0,16): all tiles full
    const int q0 = qlong * 32;
    const _Float16* qb = Qp + (((size_t)(bh * 64 + qlong) * 4) << 9) + (l << 3);
#pragma unroll
    for (int c = 0; c < 4; ++c) qf[c] = *(const half8*)(qb + (c << 9));
    RUN_RANGE(0, 16, q0);
  } else {
    // phase A: short q-tile fully, store
    const int q0s = qshort * 32;
    const int NTS = qshort / 2 + 1;
    const _Float16* qb = Qp + (((size_t)(bh * 64 + qshort) * 4) << 9) + (l << 3);
#pragma unroll
    for (int c = 0; c < 4; ++c) qf[c] = *(const half8*)(qb + (c << 9));
    RUN_RANGE(0, NTS, q0s);
    {
      const float inv = 1.f / l_run;
      _Float16* op = attC + ((size_t)b * Sc + q0s + lq) * Dc + h * 64;
#pragma unroll
      for (int g = 0; g < 4; ++g) {
        union { _Float16 hh[4]; unsigned long long u; } pA, pB;
#pragma unroll
        for (int jj = 0; jj < 4; ++jj) {
          pA.hh[jj] = (_Float16)(OA[4 * g + jj] * inv);
          pB.hh[jj] = (_Float16)(OB[4 * g + jj] * inv);
        }
        *(unsigned long long*)(op + 8 * g + 4 * hi) = pA.u;
        *(unsigned long long*)(op + 32 + 8 * g + 4 * hi) = pB.u;
      }
    }
    // phase B: long q-tile, kv [16, NTL)
    const int q0 = qlong * 32;
    const _Float16* qb2 = Qp + (((size_t)(bh * 64 + qlong) * 4) << 9) + (l << 3);
#pragma unroll
    for (int c = 0; c < 4; ++c) qf[c] = *(const half8*)(qb2 + (c << 9));
#pragma unroll
    for (int r = 0; r < 16; ++r) { OA[r] = 0.f; OB[r] = 0.f; }
    m_run = -1e30f; l_run = 0.f;
    RUN_RANGE(16, NTL, q0);
    // publish partial state
#pragma unroll
    for (int g = 0; g < 4; ++g) {
      float4 a, bq;
      a.x = OA[4 * g + 0]; a.y = OA[4 * g + 1]; a.z = OA[4 * g + 2]; a.w = OA[4 * g + 3];
      bq.x = OB[4 * g + 0]; bq.y = OB[4 * g + 1]; bq.z = OB[4 * g + 2]; bq.w = OB[4 * g + 3];
      *(float4*)&Osh[g][l][0] = a;
      *(float4*)&Osh[4 + g][l][0] = bq;
    }
    mlsh[0][l] = m_run;
    mlsh[1][l] = l_run;
  }
  __syncthreads();
  if (wv == 0) {
    // merge partial states of the long q-tile, store
    const float m1 = mlsh[0][l], l1 = mlsh[1][l];
    const float mm = fmaxf(m_run, m1);
    const float c0 = __builtin_amdgcn_exp2f(m_run - mm);
    const float c1 = __builtin_amdgcn_exp2f(m1 - mm);
    const float linv = 1.f / (l_run * c0 + l1 * c1);
    _Float16* op = attC + ((size_t)b * Sc + qlong * 32 + lq) * Dc + h * 64;
#pragma unroll
    for (int g = 0; g < 4; ++g) {
      const float4 o1a = *(const float4*)&Osh[g][l][0];
      const float4 o1b = *(const float4*)&Osh[4 + g][l][0];
      union { _Float16 hh[4]; unsigned long long u; } pA, pB;
      pA.hh[0] = (_Float16)((OA[4 * g + 0] * c0 + o1a.x * c1) * linv);
      pA.hh[1] = (_Float16)((OA[4 * g + 1] * c0 + o1a.y * c1) * linv);
      pA.hh[2] = (_Float16)((OA[4 * g + 2] * c0 + o1a.z * c1) * linv);
      pA.hh[3] = (_Float16)((OA[4 * g + 3] * c0 + o1a.w * c1) * linv);
      pB.hh[0] = (_Float16)((OB[4 * g + 0] * c0 + o1b.x * c1) * linv);
      pB.hh[1] = (_Float16)((OB[4 * g + 1] * c0 + o1b.y * c1) * linv);
      pB.hh[2] = (_Float16)((OB[4 * g + 2] * c0 + o1b.z * c1) * linv);
      pB.hh[3] = (_Float16)((OB[4 * g + 3] * c0 + o1b.w * c1) * linv);
      *(unsigned long long*)(op + 8 * g + 4 * hi) = pA.u;
      *(unsigned long long*)(op + 32 + 8 * g + 4 * hi) = pB.u;
    }
  }
}

// ---------------------------------------------------------------------------
// out_proj (R8 known-good): 64x128 tile (512 blocks), BK=32, 4 waves 1x4;
// LDS pitch padded 32->40 (near-conflict-free; pitch-72 was 8-way, R12).
__global__ __launch_bounds__(256) void out_proj(
    const _Float16* __restrict__ attC, const _Float16* __restrict__ WoT,
    const float* __restrict__ bo, float* __restrict__ out) {
  const int m0 = blockIdx.x * 64, n0 = blockIdx.y * 128;
  __shared__ __align__(16) _Float16 Alds[64][40];
  __shared__ __align__(16) _Float16 Blds[128][40];
  const int tid = threadIdx.x;
  const int l = tid & 63, w = tid >> 6;
  const int lr = l & 15, lg = l >> 4;
  f32x4 acc[4][2] = {};
  for (int kt = 0; kt < 32; ++kt) {
    const int k0 = kt * 32;
    {
      const int r = tid >> 2, c8 = (tid & 3) * 8;
      *(half8*)&Alds[r][c8] = *(const half8*)(attC + (size_t)(m0 + r) * Dc + k0 + c8);
#pragma unroll
      for (int ii = 0; ii < 2; ++ii) {
        const int g = tid + ii * 256;
        const int rb = g >> 2, cb = (g & 3) * 8;
        *(half8*)&Blds[rb][cb] = *(const half8*)(WoT + (size_t)(n0 + rb) * Dc + k0 + cb);
      }
    }
    __syncthreads();
    half8 af[4], bf[2];
#pragma unroll
    for (int i2 = 0; i2 < 4; ++i2) af[i2] = *(const half8*)&Alds[i2 * 16 + lr][lg * 8];
#pragma unroll
    for (int j = 0; j < 2; ++j) bf[j] = *(const half8*)&Blds[w * 32 + j * 16 + lr][lg * 8];
#pragma unroll
    for (int i2 = 0; i2 < 4; ++i2)
#pragma unroll
      for (int j = 0; j < 2; ++j)
        acc[i2][j] = __builtin_amdgcn_mfma_f32_16x16x32_f16(af[i2], bf[j], acc[i2][j], 0, 0, 0);
    __syncthreads();
  }
#pragma unroll
  for (int i2 = 0; i2 < 4; ++i2)
#pragma unroll
    for (int j = 0; j < 2; ++j) {
      const int n = n0 + w * 32 + j * 16 + lr;
      const float bias = bo[n];
#pragma unroll
      for (int r = 0; r < 4; ++r) {
        const int m = m0 + i2 * 16 + lg * 4 + r;
        out[(size_t)m * Dc + n] = acc[i2][j][r] + bias;
      }
    }
}

// ---------------------------------------------------------------------------
extern "C" void kernel_launch(void* const* d_in, const int* in_sizes, int n_in,
                              void* d_out, int out_size, void* d_ws, size_t ws_size,
                              hipStream_t stream) {
  const float* x  = (const float*)d_in[0];
  const float* Wq = (const float*)d_in[1];
  const float* Wk = (const float*)d_in[2];
  const float* Wv = (const float*)d_in[3];
  const float* Wo = (const float*)d_in[4];
  const float* bo = (const float*)d_in[5];
  float* out = (float*)d_out;
  char* ws = (char*)d_ws;
  _Float16* Qp   = (_Float16*)(ws);                        // [0,8M)
  _Float16* Kp   = (_Float16*)(ws + (size_t)(8  << 20));   // [8M,16M)
  _Float16* Vp   = (_Float16*)(ws + (size_t)(16 << 20));   // [16M,24M)
  _Float16* WoT  = (_Float16*)(ws + (size_t)(24 << 20));   // [24M,26M)
  _Float16* WT   = (_Float16*)(ws + (size_t)(26 << 20));   // [26M,26.4M) dead after qkv
  _Float16* attC = (_Float16*)(ws + (size_t)(26 << 20));   // [26M,34M) written in flash

  prep_all<<<dim3(304), dim3(256), 0, stream>>>(Wq, Wk, Wv, Wo, WT, WoT);
  qkv_proj<<<dim3(512), dim3(256), 0, stream>>>(x, WT, Qp, Kp, Vp);
  flash_attn<<<dim3(1024), dim3(128), 0, stream>>>(Qp, Kp, Vp, attC);
  out_proj<<<dim3(64, 8), dim3(256), 0, stream>>>(attC, WoT, bo, out);
}